// Round 1
// baseline (224.454 us; speedup 1.0000x reference)
//
#include <hip/hip_runtime.h>
#include <cstddef>

#define N_ROWS 6144
#define TRH 4           // rows per half-group (pipelined)
#define TR 8            // rows per block
#define NT 256          // threads per block
#define NBLK (N_ROWS / TR)   // 768
#define JT (NT * 4)          // j's per block-iteration (1024)
#define NIT (N_ROWS / JT)    // 6 iterations per pass
#define L2E 1.44269504088896340736f

typedef float f32x4 __attribute__((ext_vector_type(4)));

#if __has_builtin(__builtin_amdgcn_exp2f)
#define EXP2F(x) __builtin_amdgcn_exp2f(x)
#else
#define EXP2F(x) exp2f(x)
#endif
#if __has_builtin(__builtin_amdgcn_logf)
#define LOG2F(x) __builtin_amdgcn_logf(x)
#else
#define LOG2F(x) log2f(x)
#endif

__device__ __forceinline__ float wredSum(float v) {
#pragma unroll
    for (int off = 32; off > 0; off >>= 1) v += __shfl_xor(v, off, 64);
    return v;
}

// Fully fused, two-half software pipeline:
//   S1: accumulate softmax stats for rows 0..3 (no writes — half the old
//       write-idle head: per-pair core work halves, projections unchanged)
//   S2: stream a1 rows 0..3 WHILE accumulating stats for rows 4..7,
//       sharing one K/V projection per column (in-block compute/write overlap)
//   S3: reduce rows 4..7
//   S4: stream a1 rows 4..7
// Numerics are bit-identical to the previous single-pipeline version.
__global__ __launch_bounds__(NT, 2) void attn_fused(
    const float* __restrict__ x,
    const float* __restrict__ wq1, const float* __restrict__ bq1,
    const float* __restrict__ wq2, const float* __restrict__ bq2,
    const float* __restrict__ wq3, const float* __restrict__ bq3,
    const float* __restrict__ wq4, const float* __restrict__ bq4,
    const float* __restrict__ wk1, const float* __restrict__ bk1,
    const float* __restrict__ wk2, const float* __restrict__ bk2,
    const float* __restrict__ wv1, const float* __restrict__ bv1,
    const float* __restrict__ wv2, const float* __restrict__ bv2,
    const float* __restrict__ wb,  const float* __restrict__ bb,
    float* __restrict__ out)
{
    const int row0 = blockIdx.x * TR;
    const int tid  = threadIdx.x;
    const int wave = tid >> 6;
    const int lane = tid & 63;

    __shared__ float redA[4][TRH * 8];
    __shared__ float redB[4][TRH * 8];

    // ---- uniform weight prep (scalarized by compiler) ----
    float wg1[9], wg2[9], bg1[3], bg2[3];
    float k1w[9], k2w[9], v1w[9], v2w[9];
    float k1b[3], k2b[3], v1b[3], v2b[3];
#pragma unroll
    for (int t = 0; t < 9; t++) {
        wg1[t] = (wq1[t] + wq2[t]) * L2E;
        wg2[t] = (wq3[t] + wq4[t]) * L2E;
        k1w[t] = wk1[t]; k2w[t] = wk2[t];
        v1w[t] = wv1[t]; v2w[t] = wv2[t];
    }
#pragma unroll
    for (int t = 0; t < 3; t++) {
        bg1[t] = (bq1[t] + bq2[t]) * L2E;
        bg2[t] = (bq3[t] + bq4[t]) * L2E;
        k1b[t] = bk1[t]; k2b[t] = bk2[t];
        v1b[t] = bv1[t]; v2b[t] = bv2[t];
    }

    // ---- g vectors for this block's TR rows (uniform across threads) ----
    float g1x[TR], g1y[TR], g1z[TR], g2x[TR], g2y[TR], g2z[TR];
#pragma unroll
    for (int r = 0; r < TR; r++) {
        const int i = row0 + r;
        const float x0 = x[3*i+0], x1 = x[3*i+1], x2 = x[3*i+2];
        g1x[r] = wg1[0]*x0 + wg1[1]*x1 + wg1[2]*x2 + bg1[0];
        g1y[r] = wg1[3]*x0 + wg1[4]*x1 + wg1[5]*x2 + bg1[1];
        g1z[r] = wg1[6]*x0 + wg1[7]*x1 + wg1[8]*x2 + bg1[2];
        g2x[r] = wg2[0]*x0 + wg2[1]*x1 + wg2[2]*x2 + bg2[0];
        g2y[r] = wg2[3]*x0 + wg2[4]*x1 + wg2[5]*x2 + bg2[1];
        g2z[r] = wg2[6]*x0 + wg2[7]*x1 + wg2[8]*x2 + bg2[2];
    }

    float l1[TRH], l2[TRH];
    float o1x[TRH], o1y[TRH], o1z[TRH], o2x[TRH], o2y[TRH], o2z[TRH];
#pragma unroll
    for (int r = 0; r < TRH; r++) {
        l1[r]=0.f; l2[r]=0.f;
        o1x[r]=0.f; o1y[r]=0.f; o1z[r]=0.f;
        o2x[r]=0.f; o2y[r]=0.f; o2z[r]=0.f;
    }

    // ---- Stage 1: stats for rows 0..3 ----
    for (int it = 0; it < NIT; it++) {
        const int j0 = it * JT + tid * 4;
        const f32x4 xa = *(const f32x4*)(x + 3*j0);
        const f32x4 xb = *(const f32x4*)(x + 3*j0 + 4);
        const f32x4 xc = *(const f32x4*)(x + 3*j0 + 8);
        const float xs[12] = { xa.x, xa.y, xa.z, xa.w, xb.x, xb.y,
                               xb.z, xb.w, xc.x, xc.y, xc.z, xc.w };
#pragma unroll
        for (int jj = 0; jj < 4; jj++) {
            const float xx = xs[3*jj], xy = xs[3*jj+1], xz = xs[3*jj+2];
            const float k1x = k1w[0]*xx + k1w[1]*xy + k1w[2]*xz + k1b[0];
            const float k1y = k1w[3]*xx + k1w[4]*xy + k1w[5]*xz + k1b[1];
            const float k1z = k1w[6]*xx + k1w[7]*xy + k1w[8]*xz + k1b[2];
            const float k2x = k2w[0]*xx + k2w[1]*xy + k2w[2]*xz + k2b[0];
            const float k2y = k2w[3]*xx + k2w[4]*xy + k2w[5]*xz + k2b[1];
            const float k2z = k2w[6]*xx + k2w[7]*xy + k2w[8]*xz + k2b[2];
            const float v1x = v1w[0]*xx + v1w[1]*xy + v1w[2]*xz + v1b[0];
            const float v1y = v1w[3]*xx + v1w[4]*xy + v1w[5]*xz + v1b[1];
            const float v1z = v1w[6]*xx + v1w[7]*xy + v1w[8]*xz + v1b[2];
            const float v2x = v2w[0]*xx + v2w[1]*xy + v2w[2]*xz + v2b[0];
            const float v2y = v2w[3]*xx + v2w[4]*xy + v2w[5]*xz + v2b[1];
            const float v2z = v2w[6]*xx + v2w[7]*xy + v2w[8]*xz + v2b[2];
#pragma unroll
            for (int r = 0; r < TRH; r++) {
                const float t1 = fmaf(g1z[r], k1z, fmaf(g1y[r], k1y, g1x[r]*k1x));
                const float t2 = fmaf(g2z[r], k2z, fmaf(g2y[r], k2y, g2x[r]*k2x));
                const float e1 = EXP2F(t1);
                const float e2 = EXP2F(t2);
                l1[r] += e1; l2[r] += e2;
                o1x[r] = fmaf(e1, v1x, o1x[r]);
                o1y[r] = fmaf(e1, v1y, o1y[r]);
                o1z[r] = fmaf(e1, v1z, o1z[r]);
                o2x[r] = fmaf(e2, v2x, o2x[r]);
                o2y[r] = fmaf(e2, v2y, o2y[r]);
                o2z[r] = fmaf(e2, v2z, o2z[r]);
            }
        }
    }

    // ---- reduce rows 0..3 ----
#pragma unroll
    for (int r = 0; r < TRH; r++) {
        l1[r]  = wredSum(l1[r]);  l2[r]  = wredSum(l2[r]);
        o1x[r] = wredSum(o1x[r]); o1y[r] = wredSum(o1y[r]); o1z[r] = wredSum(o1z[r]);
        o2x[r] = wredSum(o2x[r]); o2y[r] = wredSum(o2y[r]); o2z[r] = wredSum(o2z[r]);
        if (lane == 0) {
            redA[wave][r*8+0]=l1[r];  redA[wave][r*8+1]=l2[r];
            redA[wave][r*8+2]=o1x[r]; redA[wave][r*8+3]=o1y[r]; redA[wave][r*8+4]=o1z[r];
            redA[wave][r*8+5]=o2x[r]; redA[wave][r*8+6]=o2y[r]; redA[wave][r*8+7]=o2z[r];
        }
    }
    __syncthreads();

    float c1pA[TRH];
#pragma unroll
    for (int r = 0; r < TRH; r++) {
        const float l1t = redA[0][r*8] + redA[1][r*8] + redA[2][r*8] + redA[3][r*8];
        c1pA[r] = -LOG2F(l1t);
    }

    // b epilogue for rows 0..3 (redA is never rewritten — no extra barrier)
    if (tid < TRH) {
        const int r = tid;
        const float l1t = redA[0][r*8+0]+redA[1][r*8+0]+redA[2][r*8+0]+redA[3][r*8+0];
        const float l2t = redA[0][r*8+1]+redA[1][r*8+1]+redA[2][r*8+1]+redA[3][r*8+1];
        const float sx1 = redA[0][r*8+2]+redA[1][r*8+2]+redA[2][r*8+2]+redA[3][r*8+2];
        const float sy1 = redA[0][r*8+3]+redA[1][r*8+3]+redA[2][r*8+3]+redA[3][r*8+3];
        const float sz1 = redA[0][r*8+4]+redA[1][r*8+4]+redA[2][r*8+4]+redA[3][r*8+4];
        const float sx2 = redA[0][r*8+5]+redA[1][r*8+5]+redA[2][r*8+5]+redA[3][r*8+5];
        const float sy2 = redA[0][r*8+6]+redA[1][r*8+6]+redA[2][r*8+6]+redA[3][r*8+6];
        const float sz2 = redA[0][r*8+7]+redA[1][r*8+7]+redA[2][r*8+7]+redA[3][r*8+7];
        const float r1 = 1.0f / l1t, r2 = 1.0f / l2t;
        const float ox = sx1*r1 + sx2*r2;
        const float oy = sy1*r1 + sy2*r2;
        const float oz = sz1*r1 + sz2*r2;
        const float b0 = wb[0]*ox + wb[1]*oy + wb[2]*oz + bb[0];
        const float b1 = wb[3]*ox + wb[4]*oy + wb[5]*oz + bb[1];
        const float b2 = wb[6]*ox + wb[7]*oy + wb[8]*oz + bb[2];
        const size_t base = (size_t)N_ROWS * N_ROWS + (size_t)(row0 + r) * 3;
        out[base+0] = b0; out[base+1] = b1; out[base+2] = b2;
    }

    // reinit accumulators for rows 4..7
#pragma unroll
    for (int r = 0; r < TRH; r++) {
        l1[r]=0.f; l2[r]=0.f;
        o1x[r]=0.f; o1y[r]=0.f; o1z[r]=0.f;
        o2x[r]=0.f; o2y[r]=0.f; o2z[r]=0.f;
    }

    // ---- Stage 2: write a1 rows 0..3 WHILE accumulating rows 4..7 ----
    for (int it = 0; it < NIT; it++) {
        const int j0 = it * JT + tid * 4;
        const f32x4 xa = *(const f32x4*)(x + 3*j0);
        const f32x4 xb = *(const f32x4*)(x + 3*j0 + 4);
        const f32x4 xc = *(const f32x4*)(x + 3*j0 + 8);
        const float xs[12] = { xa.x, xa.y, xa.z, xa.w, xb.x, xb.y,
                               xb.z, xb.w, xc.x, xc.y, xc.z, xc.w };
        float K1x[4], K1y[4], K1z[4];
#pragma unroll
        for (int jj = 0; jj < 4; jj++) {
            const float xx = xs[3*jj], xy = xs[3*jj+1], xz = xs[3*jj+2];
            const float k1x = k1w[0]*xx + k1w[1]*xy + k1w[2]*xz + k1b[0];
            const float k1y = k1w[3]*xx + k1w[4]*xy + k1w[5]*xz + k1b[1];
            const float k1z = k1w[6]*xx + k1w[7]*xy + k1w[8]*xz + k1b[2];
            K1x[jj] = k1x; K1y[jj] = k1y; K1z[jj] = k1z;
            const float k2x = k2w[0]*xx + k2w[1]*xy + k2w[2]*xz + k2b[0];
            const float k2y = k2w[3]*xx + k2w[4]*xy + k2w[5]*xz + k2b[1];
            const float k2z = k2w[6]*xx + k2w[7]*xy + k2w[8]*xz + k2b[2];
            const float v1x = v1w[0]*xx + v1w[1]*xy + v1w[2]*xz + v1b[0];
            const float v1y = v1w[3]*xx + v1w[4]*xy + v1w[5]*xz + v1b[1];
            const float v1z = v1w[6]*xx + v1w[7]*xy + v1w[8]*xz + v1b[2];
            const float v2x = v2w[0]*xx + v2w[1]*xy + v2w[2]*xz + v2b[0];
            const float v2y = v2w[3]*xx + v2w[4]*xy + v2w[5]*xz + v2b[1];
            const float v2z = v2w[6]*xx + v2w[7]*xy + v2w[8]*xz + v2b[2];
#pragma unroll
            for (int r = 0; r < TRH; r++) {
                const float t1 = fmaf(g1z[r+TRH], k1z, fmaf(g1y[r+TRH], k1y, g1x[r+TRH]*k1x));
                const float t2 = fmaf(g2z[r+TRH], k2z, fmaf(g2y[r+TRH], k2y, g2x[r+TRH]*k2x));
                const float e1 = EXP2F(t1);
                const float e2 = EXP2F(t2);
                l1[r] += e1; l2[r] += e2;
                o1x[r] = fmaf(e1, v1x, o1x[r]);
                o1y[r] = fmaf(e1, v1y, o1y[r]);
                o1z[r] = fmaf(e1, v1z, o1z[r]);
                o2x[r] = fmaf(e2, v2x, o2x[r]);
                o2y[r] = fmaf(e2, v2y, o2y[r]);
                o2z[r] = fmaf(e2, v2z, o2z[r]);
            }
        }
        // stream rows 0..3 (nontemporal)
#pragma unroll
        for (int r = 0; r < TRH; r++) {
            f32x4 pv;
            pv.x = EXP2F(fmaf(g1z[r], K1z[0], fmaf(g1y[r], K1y[0], fmaf(g1x[r], K1x[0], c1pA[r]))));
            pv.y = EXP2F(fmaf(g1z[r], K1z[1], fmaf(g1y[r], K1y[1], fmaf(g1x[r], K1x[1], c1pA[r]))));
            pv.z = EXP2F(fmaf(g1z[r], K1z[2], fmaf(g1y[r], K1y[2], fmaf(g1x[r], K1x[2], c1pA[r]))));
            pv.w = EXP2F(fmaf(g1z[r], K1z[3], fmaf(g1y[r], K1y[3], fmaf(g1x[r], K1x[3], c1pA[r]))));
            __builtin_nontemporal_store(pv, (f32x4*)(out + (size_t)(row0 + r) * N_ROWS + j0));
        }
    }

    // ---- Stage 3: reduce rows 4..7 ----
#pragma unroll
    for (int r = 0; r < TRH; r++) {
        l1[r]  = wredSum(l1[r]);  l2[r]  = wredSum(l2[r]);
        o1x[r] = wredSum(o1x[r]); o1y[r] = wredSum(o1y[r]); o1z[r] = wredSum(o1z[r]);
        o2x[r] = wredSum(o2x[r]); o2y[r] = wredSum(o2y[r]); o2z[r] = wredSum(o2z[r]);
        if (lane == 0) {
            redB[wave][r*8+0]=l1[r];  redB[wave][r*8+1]=l2[r];
            redB[wave][r*8+2]=o1x[r]; redB[wave][r*8+3]=o1y[r]; redB[wave][r*8+4]=o1z[r];
            redB[wave][r*8+5]=o2x[r]; redB[wave][r*8+6]=o2y[r]; redB[wave][r*8+7]=o2z[r];
        }
    }
    __syncthreads();

    float c1pB[TRH];
#pragma unroll
    for (int r = 0; r < TRH; r++) {
        const float l1t = redB[0][r*8] + redB[1][r*8] + redB[2][r*8] + redB[3][r*8];
        c1pB[r] = -LOG2F(l1t);
    }

    // b epilogue for rows 4..7
    if (tid < TRH) {
        const int r = tid;
        const float l1t = redB[0][r*8+0]+redB[1][r*8+0]+redB[2][r*8+0]+redB[3][r*8+0];
        const float l2t = redB[0][r*8+1]+redB[1][r*8+1]+redB[2][r*8+1]+redB[3][r*8+1];
        const float sx1 = redB[0][r*8+2]+redB[1][r*8+2]+redB[2][r*8+2]+redB[3][r*8+2];
        const float sy1 = redB[0][r*8+3]+redB[1][r*8+3]+redB[2][r*8+3]+redB[3][r*8+3];
        const float sz1 = redB[0][r*8+4]+redB[1][r*8+4]+redB[2][r*8+4]+redB[3][r*8+4];
        const float sx2 = redB[0][r*8+5]+redB[1][r*8+5]+redB[2][r*8+5]+redB[3][r*8+5];
        const float sy2 = redB[0][r*8+6]+redB[1][r*8+6]+redB[2][r*8+6]+redB[3][r*8+6];
        const float sz2 = redB[0][r*8+7]+redB[1][r*8+7]+redB[2][r*8+7]+redB[3][r*8+7];
        const float r1 = 1.0f / l1t, r2 = 1.0f / l2t;
        const float ox = sx1*r1 + sx2*r2;
        const float oy = sy1*r1 + sy2*r2;
        const float oz = sz1*r1 + sz2*r2;
        const float b0 = wb[0]*ox + wb[1]*oy + wb[2]*oz + bb[0];
        const float b1 = wb[3]*ox + wb[4]*oy + wb[5]*oz + bb[1];
        const float b2 = wb[6]*ox + wb[7]*oy + wb[8]*oz + bb[2];
        const size_t base = (size_t)N_ROWS * N_ROWS + (size_t)(row0 + TRH + r) * 3;
        out[base+0] = b0; out[base+1] = b1; out[base+2] = b2;
    }

    // ---- Stage 4: write a1 rows 4..7 ----
    for (int it = 0; it < NIT; it++) {
        const int j0 = it * JT + tid * 4;
        const f32x4 xa = *(const f32x4*)(x + 3*j0);
        const f32x4 xb = *(const f32x4*)(x + 3*j0 + 4);
        const f32x4 xc = *(const f32x4*)(x + 3*j0 + 8);
        const float xs[12] = { xa.x, xa.y, xa.z, xa.w, xb.x, xb.y,
                               xb.z, xb.w, xc.x, xc.y, xc.z, xc.w };
        float K1x[4], K1y[4], K1z[4];
#pragma unroll
        for (int jj = 0; jj < 4; jj++) {
            const float xx = xs[3*jj], xy = xs[3*jj+1], xz = xs[3*jj+2];
            K1x[jj] = k1w[0]*xx + k1w[1]*xy + k1w[2]*xz + k1b[0];
            K1y[jj] = k1w[3]*xx + k1w[4]*xy + k1w[5]*xz + k1b[1];
            K1z[jj] = k1w[6]*xx + k1w[7]*xy + k1w[8]*xz + k1b[2];
        }
#pragma unroll
        for (int r = 0; r < TRH; r++) {
            f32x4 pv;
            pv.x = EXP2F(fmaf(g1z[r+TRH], K1z[0], fmaf(g1y[r+TRH], K1y[0], fmaf(g1x[r+TRH], K1x[0], c1pB[r]))));
            pv.y = EXP2F(fmaf(g1z[r+TRH], K1z[1], fmaf(g1y[r+TRH], K1y[1], fmaf(g1x[r+TRH], K1x[1], c1pB[r]))));
            pv.z = EXP2F(fmaf(g1z[r+TRH], K1z[2], fmaf(g1y[r+TRH], K1y[2], fmaf(g1x[r+TRH], K1x[2], c1pB[r]))));
            pv.w = EXP2F(fmaf(g1z[r+TRH], K1z[3], fmaf(g1y[r+TRH], K1y[3], fmaf(g1x[r+TRH], K1x[3], c1pB[r]))));
            __builtin_nontemporal_store(pv, (f32x4*)(out + (size_t)(row0 + TRH + r) * N_ROWS + j0));
        }
    }
}

extern "C" void kernel_launch(void* const* d_in, const int* in_sizes, int n_in,
                              void* d_out, int out_size, void* d_ws, size_t ws_size,
                              hipStream_t stream) {
    const float* x   = (const float*)d_in[0];
    const float* wq1 = (const float*)d_in[1];  const float* bq1 = (const float*)d_in[2];
    const float* wq2 = (const float*)d_in[3];  const float* bq2 = (const float*)d_in[4];
    const float* wq3 = (const float*)d_in[5];  const float* bq3 = (const float*)d_in[6];
    const float* wq4 = (const float*)d_in[7];  const float* bq4 = (const float*)d_in[8];
    const float* wk1 = (const float*)d_in[9];  const float* bk1 = (const float*)d_in[10];
    const float* wk2 = (const float*)d_in[11]; const float* bk2 = (const float*)d_in[12];
    const float* wv1 = (const float*)d_in[13]; const float* bv1 = (const float*)d_in[14];
    const float* wv2 = (const float*)d_in[15]; const float* bv2 = (const float*)d_in[16];
    const float* wb  = (const float*)d_in[17]; const float* bb  = (const float*)d_in[18];

    float* out = (float*)d_out;

    attn_fused<<<NBLK, NT, 0, stream>>>(
        x, wq1,bq1, wq2,bq2, wq3,bq3, wq4,bq4,
        wk1,bk1, wk2,bk2, wv1,bv1, wv2,bv2, wb, bb, out);
}

// Round 2
// 219.027 us; speedup vs baseline: 1.0248x; 1.0248x over previous
//
#include <hip/hip_runtime.h>
#include <cstddef>

#define N_ROWS 6144
#define TR 8            // rows per block
#define NT 256          // threads per block
#define NBLK (N_ROWS / TR)   // 768
#define JT (NT * 4)          // j's per block-iteration (1024)
#define NIT (N_ROWS / JT)    // 6 iterations per pass
#define L2E 1.44269504088896340736f

typedef float f32x4 __attribute__((ext_vector_type(4)));

#if __has_builtin(__builtin_amdgcn_exp2f)
#define EXP2F(x) __builtin_amdgcn_exp2f(x)
#else
#define EXP2F(x) exp2f(x)
#endif
#if __has_builtin(__builtin_amdgcn_logf)
#define LOG2F(x) __builtin_amdgcn_logf(x)
#else
#define LOG2F(x) log2f(x)
#endif

__device__ __forceinline__ float wredSum(float v) {
#pragma unroll
    for (int off = 32; off > 0; off >>= 1) v += __shfl_xor(v, off, 64);
    return v;
}

// Fully fused, single pipeline (R1's two-half split reverted: it duplicated
// per-j projection work and regressed). R2's algebraic transform removes ALL
// per-j projections:
//   scores:  t1 = g1.(K1 x_j + bk1) = (K1^T g1).x_j + g1.bk1  -> h1[r], hc1[r]
//   PV:      o1 = V1.(sum e1 x_j) + bv1*l1                    -> accumulate s1
//   pass B:  a1[i][j] = exp2(h1.x_j + (hc1[r] - log2(l1)))
// Pass A per j per block: 8 rows x (6 fma score + 6 fma s-accum + 2 add + 2 exp),
// zero shared projection work (was 36 fma/j). Pass B: 8 x (3 fma + exp).
__global__ __launch_bounds__(NT, 2) void attn_fused(
    const float* __restrict__ x,
    const float* __restrict__ wq1, const float* __restrict__ bq1,
    const float* __restrict__ wq2, const float* __restrict__ bq2,
    const float* __restrict__ wq3, const float* __restrict__ bq3,
    const float* __restrict__ wq4, const float* __restrict__ bq4,
    const float* __restrict__ wk1, const float* __restrict__ bk1,
    const float* __restrict__ wk2, const float* __restrict__ bk2,
    const float* __restrict__ wv1, const float* __restrict__ bv1,
    const float* __restrict__ wv2, const float* __restrict__ bv2,
    const float* __restrict__ wb,  const float* __restrict__ bb,
    float* __restrict__ out)
{
    const int row0 = blockIdx.x * TR;
    const int tid  = threadIdx.x;
    const int wave = tid >> 6;
    const int lane = tid & 63;

    __shared__ float red[4][64];

    // ---- uniform weight prep (scalarized by compiler) ----
    float wg1[9], wg2[9], bg1[3], bg2[3];
    float k1w[9], k2w[9], v1w[9], v2w[9];
    float k1b[3], k2b[3], v1b[3], v2b[3];
#pragma unroll
    for (int t = 0; t < 9; t++) {
        wg1[t] = (wq1[t] + wq2[t]) * L2E;
        wg2[t] = (wq3[t] + wq4[t]) * L2E;
        k1w[t] = wk1[t]; k2w[t] = wk2[t];
        v1w[t] = wv1[t]; v2w[t] = wv2[t];
    }
#pragma unroll
    for (int t = 0; t < 3; t++) {
        bg1[t] = (bq1[t] + bq2[t]) * L2E;
        bg2[t] = (bq3[t] + bq4[t]) * L2E;
        k1b[t] = bk1[t]; k2b[t] = bk2[t];
        v1b[t] = bv1[t]; v2b[t] = bv2[t];
    }

    // ---- per-row folded score vectors: h = K^T g, hc = g.bk (block-uniform) ----
    float h1x[TR], h1y[TR], h1z[TR], hc1[TR];
    float h2x[TR], h2y[TR], h2z[TR], hc2[TR];
#pragma unroll
    for (int r = 0; r < TR; r++) {
        const int i = row0 + r;
        const float x0 = x[3*i+0], x1 = x[3*i+1], x2 = x[3*i+2];
        const float g1a = wg1[0]*x0 + wg1[1]*x1 + wg1[2]*x2 + bg1[0];
        const float g1b = wg1[3]*x0 + wg1[4]*x1 + wg1[5]*x2 + bg1[1];
        const float g1c = wg1[6]*x0 + wg1[7]*x1 + wg1[8]*x2 + bg1[2];
        const float g2a = wg2[0]*x0 + wg2[1]*x1 + wg2[2]*x2 + bg2[0];
        const float g2b = wg2[3]*x0 + wg2[4]*x1 + wg2[5]*x2 + bg2[1];
        const float g2c = wg2[6]*x0 + wg2[7]*x1 + wg2[8]*x2 + bg2[2];
        // h1 = K1^T g1  (K row-major [out][in]: col t of K1 is k1w[t], k1w[t+3], k1w[t+6])
        h1x[r] = k1w[0]*g1a + k1w[3]*g1b + k1w[6]*g1c;
        h1y[r] = k1w[1]*g1a + k1w[4]*g1b + k1w[7]*g1c;
        h1z[r] = k1w[2]*g1a + k1w[5]*g1b + k1w[8]*g1c;
        hc1[r] = k1b[0]*g1a + k1b[1]*g1b + k1b[2]*g1c;
        h2x[r] = k2w[0]*g2a + k2w[3]*g2b + k2w[6]*g2c;
        h2y[r] = k2w[1]*g2a + k2w[4]*g2b + k2w[7]*g2c;
        h2z[r] = k2w[2]*g2a + k2w[5]*g2b + k2w[8]*g2c;
        hc2[r] = k2b[0]*g2a + k2b[1]*g2b + k2b[2]*g2c;
    }

    // ---- Pass A: l1,l2 and weighted-x sums s1,s2 ----
    float l1[TR], l2[TR];
    float s1x[TR], s1y[TR], s1z[TR], s2x[TR], s2y[TR], s2z[TR];
#pragma unroll
    for (int r = 0; r < TR; r++) {
        l1[r]=0.f; l2[r]=0.f;
        s1x[r]=0.f; s1y[r]=0.f; s1z[r]=0.f;
        s2x[r]=0.f; s2y[r]=0.f; s2z[r]=0.f;
    }

    for (int it = 0; it < NIT; it++) {
        const int j0 = it * JT + tid * 4;
        const f32x4 xa = *(const f32x4*)(x + 3*j0);
        const f32x4 xb = *(const f32x4*)(x + 3*j0 + 4);
        const f32x4 xc = *(const f32x4*)(x + 3*j0 + 8);
        const float xs[12] = { xa.x, xa.y, xa.z, xa.w, xb.x, xb.y,
                               xb.z, xb.w, xc.x, xc.y, xc.z, xc.w };
#pragma unroll
        for (int jj = 0; jj < 4; jj++) {
            const float xx = xs[3*jj], xy = xs[3*jj+1], xz = xs[3*jj+2];
#pragma unroll
            for (int r = 0; r < TR; r++) {
                const float t1 = fmaf(h1z[r], xz, fmaf(h1y[r], xy, fmaf(h1x[r], xx, hc1[r])));
                const float t2 = fmaf(h2z[r], xz, fmaf(h2y[r], xy, fmaf(h2x[r], xx, hc2[r])));
                const float e1 = EXP2F(t1);
                const float e2 = EXP2F(t2);
                l1[r] += e1; l2[r] += e2;
                s1x[r] = fmaf(e1, xx, s1x[r]);
                s1y[r] = fmaf(e1, xy, s1y[r]);
                s1z[r] = fmaf(e1, xz, s1z[r]);
                s2x[r] = fmaf(e2, xx, s2x[r]);
                s2y[r] = fmaf(e2, xy, s2y[r]);
                s2z[r] = fmaf(e2, xz, s2z[r]);
            }
        }
    }

    // ---- block reduce ----
#pragma unroll
    for (int r = 0; r < TR; r++) {
        l1[r]  = wredSum(l1[r]);  l2[r]  = wredSum(l2[r]);
        s1x[r] = wredSum(s1x[r]); s1y[r] = wredSum(s1y[r]); s1z[r] = wredSum(s1z[r]);
        s2x[r] = wredSum(s2x[r]); s2y[r] = wredSum(s2y[r]); s2z[r] = wredSum(s2z[r]);
        if (lane == 0) {
            red[wave][r*8+0]=l1[r];  red[wave][r*8+1]=l2[r];
            red[wave][r*8+2]=s1x[r]; red[wave][r*8+3]=s1y[r]; red[wave][r*8+4]=s1z[r];
            red[wave][r*8+5]=s2x[r]; red[wave][r*8+6]=s2y[r]; red[wave][r*8+7]=s2z[r];
        }
    }
    __syncthreads();

    // normalization folded into exponent constant
    float cc1[TR];
#pragma unroll
    for (int r = 0; r < TR; r++) {
        const float l1t = red[0][r*8] + red[1][r*8] + red[2][r*8] + red[3][r*8];
        cc1[r] = hc1[r] - LOG2F(l1t);
    }

    // ---- Pass B: write a1 (nontemporal stream) ----
    for (int it = 0; it < NIT; it++) {
        const int j0 = it * JT + tid * 4;
        const f32x4 xa = *(const f32x4*)(x + 3*j0);
        const f32x4 xb = *(const f32x4*)(x + 3*j0 + 4);
        const f32x4 xc = *(const f32x4*)(x + 3*j0 + 8);
        const float xs[12] = { xa.x, xa.y, xa.z, xa.w, xb.x, xb.y,
                               xb.z, xb.w, xc.x, xc.y, xc.z, xc.w };
#pragma unroll
        for (int r = 0; r < TR; r++) {
            f32x4 pv;
            pv.x = EXP2F(fmaf(h1z[r], xs[2],  fmaf(h1y[r], xs[1],  fmaf(h1x[r], xs[0],  cc1[r]))));
            pv.y = EXP2F(fmaf(h1z[r], xs[5],  fmaf(h1y[r], xs[4],  fmaf(h1x[r], xs[3],  cc1[r]))));
            pv.z = EXP2F(fmaf(h1z[r], xs[8],  fmaf(h1y[r], xs[7],  fmaf(h1x[r], xs[6],  cc1[r]))));
            pv.w = EXP2F(fmaf(h1z[r], xs[11], fmaf(h1y[r], xs[10], fmaf(h1x[r], xs[9],  cc1[r]))));
            __builtin_nontemporal_store(pv, (f32x4*)(out + (size_t)(row0 + r) * N_ROWS + j0));
        }
    }

    // ---- epilogue: b = Wb*(V1*(s1/l1)+bv1 + V2*(s2/l2)+bv2) + bb ----
    if (tid < TR) {
        const int r = tid;
        const float l1t = red[0][r*8+0]+red[1][r*8+0]+red[2][r*8+0]+red[3][r*8+0];
        const float l2t = red[0][r*8+1]+red[1][r*8+1]+red[2][r*8+1]+red[3][r*8+1];
        const float ux1 = (red[0][r*8+2]+red[1][r*8+2]+red[2][r*8+2]+red[3][r*8+2]) / l1t;
        const float uy1 = (red[0][r*8+3]+red[1][r*8+3]+red[2][r*8+3]+red[3][r*8+3]) / l1t;
        const float uz1 = (red[0][r*8+4]+red[1][r*8+4]+red[2][r*8+4]+red[3][r*8+4]) / l1t;
        const float ux2 = (red[0][r*8+5]+red[1][r*8+5]+red[2][r*8+5]+red[3][r*8+5]) / l2t;
        const float uy2 = (red[0][r*8+6]+red[1][r*8+6]+red[2][r*8+6]+red[3][r*8+6]) / l2t;
        const float uz2 = (red[0][r*8+7]+red[1][r*8+7]+red[2][r*8+7]+red[3][r*8+7]) / l2t;
        // normalized o = V1*u1 + bv1 + V2*u2 + bv2
        const float ox = v1w[0]*ux1 + v1w[1]*uy1 + v1w[2]*uz1 + v1b[0]
                       + v2w[0]*ux2 + v2w[1]*uy2 + v2w[2]*uz2 + v2b[0];
        const float oy = v1w[3]*ux1 + v1w[4]*uy1 + v1w[5]*uz1 + v1b[1]
                       + v2w[3]*ux2 + v2w[4]*uy2 + v2w[5]*uz2 + v2b[1];
        const float oz = v1w[6]*ux1 + v1w[7]*uy1 + v1w[8]*uz1 + v1b[2]
                       + v2w[6]*ux2 + v2w[7]*uy2 + v2w[8]*uz2 + v2b[2];
        const float b0 = wb[0]*ox + wb[1]*oy + wb[2]*oz + bb[0];
        const float b1 = wb[3]*ox + wb[4]*oy + wb[5]*oz + bb[1];
        const float b2 = wb[6]*ox + wb[7]*oy + wb[8]*oz + bb[2];
        const size_t base = (size_t)N_ROWS * N_ROWS + (size_t)(row0 + r) * 3;
        out[base+0] = b0; out[base+1] = b1; out[base+2] = b2;
    }
}

extern "C" void kernel_launch(void* const* d_in, const int* in_sizes, int n_in,
                              void* d_out, int out_size, void* d_ws, size_t ws_size,
                              hipStream_t stream) {
    const float* x   = (const float*)d_in[0];
    const float* wq1 = (const float*)d_in[1];  const float* bq1 = (const float*)d_in[2];
    const float* wq2 = (const float*)d_in[3];  const float* bq2 = (const float*)d_in[4];
    const float* wq3 = (const float*)d_in[5];  const float* bq3 = (const float*)d_in[6];
    const float* wq4 = (const float*)d_in[7];  const float* bq4 = (const float*)d_in[8];
    const float* wk1 = (const float*)d_in[9];  const float* bk1 = (const float*)d_in[10];
    const float* wk2 = (const float*)d_in[11]; const float* bk2 = (const float*)d_in[12];
    const float* wv1 = (const float*)d_in[13]; const float* bv1 = (const float*)d_in[14];
    const float* wv2 = (const float*)d_in[15]; const float* bv2 = (const float*)d_in[16];
    const float* wb  = (const float*)d_in[17]; const float* bb  = (const float*)d_in[18];

    float* out = (float*)d_out;

    attn_fused<<<NBLK, NT, 0, stream>>>(
        x, wq1,bq1, wq2,bq2, wq3,bq3, wq4,bq4,
        wk1,bk1, wk2,bk2, wv1,bv1, wv2,bv2, wb, bb, out);
}

// Round 3
// 207.317 us; speedup vs baseline: 1.0827x; 1.0565x over previous
//
#include <hip/hip_runtime.h>
#include <cstddef>

#define N_ROWS 6144
#define TR 4            // rows per block (R3: halved to shrink round-1 pass-A exposure)
#define NT 256          // threads per block
#define NBLK (N_ROWS / TR)   // 1536
#define JT (NT * 4)          // j's per block-iteration (1024)
#define NIT (N_ROWS / JT)    // 6 iterations per pass
#define L2E 1.44269504088896340736f

typedef float f32x4 __attribute__((ext_vector_type(4)));

#if __has_builtin(__builtin_amdgcn_exp2f)
#define EXP2F(x) __builtin_amdgcn_exp2f(x)
#else
#define EXP2F(x) exp2f(x)
#endif
#if __has_builtin(__builtin_amdgcn_logf)
#define LOG2F(x) __builtin_amdgcn_logf(x)
#else
#define LOG2F(x) log2f(x)
#endif

__device__ __forceinline__ float wredSum(float v) {
#pragma unroll
    for (int off = 32; off > 0; off >>= 1) v += __shfl_xor(v, off, 64);
    return v;
}

// Fully fused. R2's algebraic transform (no per-j projections):
//   scores:  t1 = (K1^T g1).x_j + g1.bk1           -> h1[r], hc1[r]
//   PV:      o1 = V1.(sum e1 x_j) + bv1*l1         -> accumulate s1 only
//   pass B:  a1[i][j] = exp2(h1.x_j + (hc1[r] - log2(l1)))
// R3: TR=4 (1536 blocks). Only the first co-resident cohort's pass A is
// exposed (write pipe idle); its cost scales with TR. Later rounds' pass A
// hides under the 151 MB a1 write stream (VALU has ~3x headroom there).
__global__ __launch_bounds__(NT, 2) void attn_fused(
    const float* __restrict__ x,
    const float* __restrict__ wq1, const float* __restrict__ bq1,
    const float* __restrict__ wq2, const float* __restrict__ bq2,
    const float* __restrict__ wq3, const float* __restrict__ bq3,
    const float* __restrict__ wq4, const float* __restrict__ bq4,
    const float* __restrict__ wk1, const float* __restrict__ bk1,
    const float* __restrict__ wk2, const float* __restrict__ bk2,
    const float* __restrict__ wv1, const float* __restrict__ bv1,
    const float* __restrict__ wv2, const float* __restrict__ bv2,
    const float* __restrict__ wb,  const float* __restrict__ bb,
    float* __restrict__ out)
{
    const int row0 = blockIdx.x * TR;
    const int tid  = threadIdx.x;
    const int wave = tid >> 6;
    const int lane = tid & 63;

    __shared__ float red[4][TR * 8];

    // ---- uniform weight prep (scalarized by compiler) ----
    float wg1[9], wg2[9], bg1[3], bg2[3];
    float k1w[9], k2w[9], v1w[9], v2w[9];
    float k1b[3], k2b[3], v1b[3], v2b[3];
#pragma unroll
    for (int t = 0; t < 9; t++) {
        wg1[t] = (wq1[t] + wq2[t]) * L2E;
        wg2[t] = (wq3[t] + wq4[t]) * L2E;
        k1w[t] = wk1[t]; k2w[t] = wk2[t];
        v1w[t] = wv1[t]; v2w[t] = wv2[t];
    }
#pragma unroll
    for (int t = 0; t < 3; t++) {
        bg1[t] = (bq1[t] + bq2[t]) * L2E;
        bg2[t] = (bq3[t] + bq4[t]) * L2E;
        k1b[t] = bk1[t]; k2b[t] = bk2[t];
        v1b[t] = bv1[t]; v2b[t] = bv2[t];
    }

    // ---- per-row folded score vectors: h = K^T g, hc = g.bk (block-uniform) ----
    float h1x[TR], h1y[TR], h1z[TR], hc1[TR];
    float h2x[TR], h2y[TR], h2z[TR], hc2[TR];
#pragma unroll
    for (int r = 0; r < TR; r++) {
        const int i = row0 + r;
        const float x0 = x[3*i+0], x1 = x[3*i+1], x2 = x[3*i+2];
        const float g1a = wg1[0]*x0 + wg1[1]*x1 + wg1[2]*x2 + bg1[0];
        const float g1b = wg1[3]*x0 + wg1[4]*x1 + wg1[5]*x2 + bg1[1];
        const float g1c = wg1[6]*x0 + wg1[7]*x1 + wg1[8]*x2 + bg1[2];
        const float g2a = wg2[0]*x0 + wg2[1]*x1 + wg2[2]*x2 + bg2[0];
        const float g2b = wg2[3]*x0 + wg2[4]*x1 + wg2[5]*x2 + bg2[1];
        const float g2c = wg2[6]*x0 + wg2[7]*x1 + wg2[8]*x2 + bg2[2];
        // h1 = K1^T g1  (K row-major [out][in]: col t of K1 is k1w[t], k1w[t+3], k1w[t+6])
        h1x[r] = k1w[0]*g1a + k1w[3]*g1b + k1w[6]*g1c;
        h1y[r] = k1w[1]*g1a + k1w[4]*g1b + k1w[7]*g1c;
        h1z[r] = k1w[2]*g1a + k1w[5]*g1b + k1w[8]*g1c;
        hc1[r] = k1b[0]*g1a + k1b[1]*g1b + k1b[2]*g1c;
        h2x[r] = k2w[0]*g2a + k2w[3]*g2b + k2w[6]*g2c;
        h2y[r] = k2w[1]*g2a + k2w[4]*g2b + k2w[7]*g2c;
        h2z[r] = k2w[2]*g2a + k2w[5]*g2b + k2w[8]*g2c;
        hc2[r] = k2b[0]*g2a + k2b[1]*g2b + k2b[2]*g2c;
    }

    // ---- Pass A: l1,l2 and weighted-x sums s1,s2 ----
    float l1[TR], l2[TR];
    float s1x[TR], s1y[TR], s1z[TR], s2x[TR], s2y[TR], s2z[TR];
#pragma unroll
    for (int r = 0; r < TR; r++) {
        l1[r]=0.f; l2[r]=0.f;
        s1x[r]=0.f; s1y[r]=0.f; s1z[r]=0.f;
        s2x[r]=0.f; s2y[r]=0.f; s2z[r]=0.f;
    }

    for (int it = 0; it < NIT; it++) {
        const int j0 = it * JT + tid * 4;
        const f32x4 xa = *(const f32x4*)(x + 3*j0);
        const f32x4 xb = *(const f32x4*)(x + 3*j0 + 4);
        const f32x4 xc = *(const f32x4*)(x + 3*j0 + 8);
        const float xs[12] = { xa.x, xa.y, xa.z, xa.w, xb.x, xb.y,
                               xb.z, xb.w, xc.x, xc.y, xc.z, xc.w };
#pragma unroll
        for (int jj = 0; jj < 4; jj++) {
            const float xx = xs[3*jj], xy = xs[3*jj+1], xz = xs[3*jj+2];
#pragma unroll
            for (int r = 0; r < TR; r++) {
                const float t1 = fmaf(h1z[r], xz, fmaf(h1y[r], xy, fmaf(h1x[r], xx, hc1[r])));
                const float t2 = fmaf(h2z[r], xz, fmaf(h2y[r], xy, fmaf(h2x[r], xx, hc2[r])));
                const float e1 = EXP2F(t1);
                const float e2 = EXP2F(t2);
                l1[r] += e1; l2[r] += e2;
                s1x[r] = fmaf(e1, xx, s1x[r]);
                s1y[r] = fmaf(e1, xy, s1y[r]);
                s1z[r] = fmaf(e1, xz, s1z[r]);
                s2x[r] = fmaf(e2, xx, s2x[r]);
                s2y[r] = fmaf(e2, xy, s2y[r]);
                s2z[r] = fmaf(e2, xz, s2z[r]);
            }
        }
    }

    // ---- block reduce ----
#pragma unroll
    for (int r = 0; r < TR; r++) {
        l1[r]  = wredSum(l1[r]);  l2[r]  = wredSum(l2[r]);
        s1x[r] = wredSum(s1x[r]); s1y[r] = wredSum(s1y[r]); s1z[r] = wredSum(s1z[r]);
        s2x[r] = wredSum(s2x[r]); s2y[r] = wredSum(s2y[r]); s2z[r] = wredSum(s2z[r]);
        if (lane == 0) {
            red[wave][r*8+0]=l1[r];  red[wave][r*8+1]=l2[r];
            red[wave][r*8+2]=s1x[r]; red[wave][r*8+3]=s1y[r]; red[wave][r*8+4]=s1z[r];
            red[wave][r*8+5]=s2x[r]; red[wave][r*8+6]=s2y[r]; red[wave][r*8+7]=s2z[r];
        }
    }
    __syncthreads();

    // normalization folded into exponent constant
    float cc1[TR];
#pragma unroll
    for (int r = 0; r < TR; r++) {
        const float l1t = red[0][r*8] + red[1][r*8] + red[2][r*8] + red[3][r*8];
        cc1[r] = hc1[r] - LOG2F(l1t);
    }

    // ---- Pass B: write a1 (nontemporal stream) ----
    for (int it = 0; it < NIT; it++) {
        const int j0 = it * JT + tid * 4;
        const f32x4 xa = *(const f32x4*)(x + 3*j0);
        const f32x4 xb = *(const f32x4*)(x + 3*j0 + 4);
        const f32x4 xc = *(const f32x4*)(x + 3*j0 + 8);
        const float xs[12] = { xa.x, xa.y, xa.z, xa.w, xb.x, xb.y,
                               xb.z, xb.w, xc.x, xc.y, xc.z, xc.w };
#pragma unroll
        for (int r = 0; r < TR; r++) {
            f32x4 pv;
            pv.x = EXP2F(fmaf(h1z[r], xs[2],  fmaf(h1y[r], xs[1],  fmaf(h1x[r], xs[0],  cc1[r]))));
            pv.y = EXP2F(fmaf(h1z[r], xs[5],  fmaf(h1y[r], xs[4],  fmaf(h1x[r], xs[3],  cc1[r]))));
            pv.z = EXP2F(fmaf(h1z[r], xs[8],  fmaf(h1y[r], xs[7],  fmaf(h1x[r], xs[6],  cc1[r]))));
            pv.w = EXP2F(fmaf(h1z[r], xs[11], fmaf(h1y[r], xs[10], fmaf(h1x[r], xs[9],  cc1[r]))));
            __builtin_nontemporal_store(pv, (f32x4*)(out + (size_t)(row0 + r) * N_ROWS + j0));
        }
    }

    // ---- epilogue: b = Wb*(V1*(s1/l1)+bv1 + V2*(s2/l2)+bv2) + bb ----
    if (tid < TR) {
        const int r = tid;
        const float l1t = red[0][r*8+0]+red[1][r*8+0]+red[2][r*8+0]+red[3][r*8+0];
        const float l2t = red[0][r*8+1]+red[1][r*8+1]+red[2][r*8+1]+red[3][r*8+1];
        const float ux1 = (red[0][r*8+2]+red[1][r*8+2]+red[2][r*8+2]+red[3][r*8+2]) / l1t;
        const float uy1 = (red[0][r*8+3]+red[1][r*8+3]+red[2][r*8+3]+red[3][r*8+3]) / l1t;
        const float uz1 = (red[0][r*8+4]+red[1][r*8+4]+red[2][r*8+4]+red[3][r*8+4]) / l1t;
        const float ux2 = (red[0][r*8+5]+red[1][r*8+5]+red[2][r*8+5]+red[3][r*8+5]) / l2t;
        const float uy2 = (red[0][r*8+6]+red[1][r*8+6]+red[2][r*8+6]+red[3][r*8+6]) / l2t;
        const float uz2 = (red[0][r*8+7]+red[1][r*8+7]+red[2][r*8+7]+red[3][r*8+7]) / l2t;
        // normalized o = V1*u1 + bv1 + V2*u2 + bv2
        const float ox = v1w[0]*ux1 + v1w[1]*uy1 + v1w[2]*uz1 + v1b[0]
                       + v2w[0]*ux2 + v2w[1]*uy2 + v2w[2]*uz2 + v2b[0];
        const float oy = v1w[3]*ux1 + v1w[4]*uy1 + v1w[5]*uz1 + v1b[1]
                       + v2w[3]*ux2 + v2w[4]*uy2 + v2w[5]*uz2 + v2b[1];
        const float oz = v1w[6]*ux1 + v1w[7]*uy1 + v1w[8]*uz1 + v1b[2]
                       + v2w[6]*ux2 + v2w[7]*uy2 + v2w[8]*uz2 + v2b[2];
        const float b0 = wb[0]*ox + wb[1]*oy + wb[2]*oz + bb[0];
        const float b1 = wb[3]*ox + wb[4]*oy + wb[5]*oz + bb[1];
        const float b2 = wb[6]*ox + wb[7]*oy + wb[8]*oz + bb[2];
        const size_t base = (size_t)N_ROWS * N_ROWS + (size_t)(row0 + r) * 3;
        out[base+0] = b0; out[base+1] = b1; out[base+2] = b2;
    }
}

extern "C" void kernel_launch(void* const* d_in, const int* in_sizes, int n_in,
                              void* d_out, int out_size, void* d_ws, size_t ws_size,
                              hipStream_t stream) {
    const float* x   = (const float*)d_in[0];
    const float* wq1 = (const float*)d_in[1];  const float* bq1 = (const float*)d_in[2];
    const float* wq2 = (const float*)d_in[3];  const float* bq2 = (const float*)d_in[4];
    const float* wq3 = (const float*)d_in[5];  const float* bq3 = (const float*)d_in[6];
    const float* wq4 = (const float*)d_in[7];  const float* bq4 = (const float*)d_in[8];
    const float* wk1 = (const float*)d_in[9];  const float* bk1 = (const float*)d_in[10];
    const float* wk2 = (const float*)d_in[11]; const float* bk2 = (const float*)d_in[12];
    const float* wv1 = (const float*)d_in[13]; const float* bv1 = (const float*)d_in[14];
    const float* wv2 = (const float*)d_in[15]; const float* bv2 = (const float*)d_in[16];
    const float* wb  = (const float*)d_in[17]; const float* bb  = (const float*)d_in[18];

    float* out = (float*)d_out;

    attn_fused<<<NBLK, NT, 0, stream>>>(
        x, wq1,bq1, wq2,bq2, wq3,bq3, wq4,bq4,
        wk1,bk1, wk2,bk2, wv1,bv1, wv2,bv2, wb, bb, out);
}

// Round 4
// 205.982 us; speedup vs baseline: 1.0897x; 1.0065x over previous
//
#include <hip/hip_runtime.h>
#include <cstddef>

#define N_ROWS 6144
#define TR 2            // rows per block (R4: halved again; R=6 rounds hides pass-A head)
#define NT 256          // threads per block
#define NBLK (N_ROWS / TR)   // 3072
#define JT (NT * 4)          // j's per block-iteration (1024)
#define NIT (N_ROWS / JT)    // 6 iterations per pass
#define L2E 1.44269504088896340736f

typedef float f32x4 __attribute__((ext_vector_type(4)));

#if __has_builtin(__builtin_amdgcn_exp2f)
#define EXP2F(x) __builtin_amdgcn_exp2f(x)
#else
#define EXP2F(x) exp2f(x)
#endif
#if __has_builtin(__builtin_amdgcn_logf)
#define LOG2F(x) __builtin_amdgcn_logf(x)
#else
#define LOG2F(x) log2f(x)
#endif

__device__ __forceinline__ float wredSum(float v) {
#pragma unroll
    for (int off = 32; off > 0; off >>= 1) v += __shfl_xor(v, off, 64);
    return v;
}

// Fully fused. R2 algebraic transform (no per-j projections):
//   scores:  t1 = (K1^T g1).x_j + g1.bk1           -> h1[r], hc1[r]
//   PV:      o1 = V1.(sum e1 x_j) + bv1*l1         -> accumulate s1 only
//   pass B:  a1[i][j] = exp2(h1.x_j + (hc1[r] - log2(l1)))
// R3/R4: a1 (151 MB) fits in the 256 MB Infinity Cache, so pass-B stores
// drain at L3 rate; kernel is jointly VALU/L3-bound. Shrinking TR raises the
// round count R (= NBLK / (256 CU * 2 blk/CU)), hiding the first-cohort
// pass-A head (A_total/R) under earlier cohorts' write streams.
__global__ __launch_bounds__(NT, 2) void attn_fused(
    const float* __restrict__ x,
    const float* __restrict__ wq1, const float* __restrict__ bq1,
    const float* __restrict__ wq2, const float* __restrict__ bq2,
    const float* __restrict__ wq3, const float* __restrict__ bq3,
    const float* __restrict__ wq4, const float* __restrict__ bq4,
    const float* __restrict__ wk1, const float* __restrict__ bk1,
    const float* __restrict__ wk2, const float* __restrict__ bk2,
    const float* __restrict__ wv1, const float* __restrict__ bv1,
    const float* __restrict__ wv2, const float* __restrict__ bv2,
    const float* __restrict__ wb,  const float* __restrict__ bb,
    float* __restrict__ out)
{
    const int row0 = blockIdx.x * TR;
    const int tid  = threadIdx.x;
    const int wave = tid >> 6;
    const int lane = tid & 63;

    __shared__ float red[4][TR * 8];

    // ---- uniform weight prep (scalarized by compiler) ----
    float wg1[9], wg2[9], bg1[3], bg2[3];
    float k1w[9], k2w[9], v1w[9], v2w[9];
    float k1b[3], k2b[3], v1b[3], v2b[3];
#pragma unroll
    for (int t = 0; t < 9; t++) {
        wg1[t] = (wq1[t] + wq2[t]) * L2E;
        wg2[t] = (wq3[t] + wq4[t]) * L2E;
        k1w[t] = wk1[t]; k2w[t] = wk2[t];
        v1w[t] = wv1[t]; v2w[t] = wv2[t];
    }
#pragma unroll
    for (int t = 0; t < 3; t++) {
        bg1[t] = (bq1[t] + bq2[t]) * L2E;
        bg2[t] = (bq3[t] + bq4[t]) * L2E;
        k1b[t] = bk1[t]; k2b[t] = bk2[t];
        v1b[t] = bv1[t]; v2b[t] = bv2[t];
    }

    // ---- per-row folded score vectors: h = K^T g, hc = g.bk (block-uniform) ----
    float h1x[TR], h1y[TR], h1z[TR], hc1[TR];
    float h2x[TR], h2y[TR], h2z[TR], hc2[TR];
#pragma unroll
    for (int r = 0; r < TR; r++) {
        const int i = row0 + r;
        const float x0 = x[3*i+0], x1 = x[3*i+1], x2 = x[3*i+2];
        const float g1a = wg1[0]*x0 + wg1[1]*x1 + wg1[2]*x2 + bg1[0];
        const float g1b = wg1[3]*x0 + wg1[4]*x1 + wg1[5]*x2 + bg1[1];
        const float g1c = wg1[6]*x0 + wg1[7]*x1 + wg1[8]*x2 + bg1[2];
        const float g2a = wg2[0]*x0 + wg2[1]*x1 + wg2[2]*x2 + bg2[0];
        const float g2b = wg2[3]*x0 + wg2[4]*x1 + wg2[5]*x2 + bg2[1];
        const float g2c = wg2[6]*x0 + wg2[7]*x1 + wg2[8]*x2 + bg2[2];
        // h1 = K1^T g1  (K row-major [out][in]: col t of K1 is k1w[t], k1w[t+3], k1w[t+6])
        h1x[r] = k1w[0]*g1a + k1w[3]*g1b + k1w[6]*g1c;
        h1y[r] = k1w[1]*g1a + k1w[4]*g1b + k1w[7]*g1c;
        h1z[r] = k1w[2]*g1a + k1w[5]*g1b + k1w[8]*g1c;
        hc1[r] = k1b[0]*g1a + k1b[1]*g1b + k1b[2]*g1c;
        h2x[r] = k2w[0]*g2a + k2w[3]*g2b + k2w[6]*g2c;
        h2y[r] = k2w[1]*g2a + k2w[4]*g2b + k2w[7]*g2c;
        h2z[r] = k2w[2]*g2a + k2w[5]*g2b + k2w[8]*g2c;
        hc2[r] = k2b[0]*g2a + k2b[1]*g2b + k2b[2]*g2c;
    }

    // ---- Pass A: l1,l2 and weighted-x sums s1,s2 ----
    float l1[TR], l2[TR];
    float s1x[TR], s1y[TR], s1z[TR], s2x[TR], s2y[TR], s2z[TR];
#pragma unroll
    for (int r = 0; r < TR; r++) {
        l1[r]=0.f; l2[r]=0.f;
        s1x[r]=0.f; s1y[r]=0.f; s1z[r]=0.f;
        s2x[r]=0.f; s2y[r]=0.f; s2z[r]=0.f;
    }

    for (int it = 0; it < NIT; it++) {
        const int j0 = it * JT + tid * 4;
        const f32x4 xa = *(const f32x4*)(x + 3*j0);
        const f32x4 xb = *(const f32x4*)(x + 3*j0 + 4);
        const f32x4 xc = *(const f32x4*)(x + 3*j0 + 8);
        const float xs[12] = { xa.x, xa.y, xa.z, xa.w, xb.x, xb.y,
                               xb.z, xb.w, xc.x, xc.y, xc.z, xc.w };
#pragma unroll
        for (int jj = 0; jj < 4; jj++) {
            const float xx = xs[3*jj], xy = xs[3*jj+1], xz = xs[3*jj+2];
#pragma unroll
            for (int r = 0; r < TR; r++) {
                const float t1 = fmaf(h1z[r], xz, fmaf(h1y[r], xy, fmaf(h1x[r], xx, hc1[r])));
                const float t2 = fmaf(h2z[r], xz, fmaf(h2y[r], xy, fmaf(h2x[r], xx, hc2[r])));
                const float e1 = EXP2F(t1);
                const float e2 = EXP2F(t2);
                l1[r] += e1; l2[r] += e2;
                s1x[r] = fmaf(e1, xx, s1x[r]);
                s1y[r] = fmaf(e1, xy, s1y[r]);
                s1z[r] = fmaf(e1, xz, s1z[r]);
                s2x[r] = fmaf(e2, xx, s2x[r]);
                s2y[r] = fmaf(e2, xy, s2y[r]);
                s2z[r] = fmaf(e2, xz, s2z[r]);
            }
        }
    }

    // ---- block reduce ----
#pragma unroll
    for (int r = 0; r < TR; r++) {
        l1[r]  = wredSum(l1[r]);  l2[r]  = wredSum(l2[r]);
        s1x[r] = wredSum(s1x[r]); s1y[r] = wredSum(s1y[r]); s1z[r] = wredSum(s1z[r]);
        s2x[r] = wredSum(s2x[r]); s2y[r] = wredSum(s2y[r]); s2z[r] = wredSum(s2z[r]);
        if (lane == 0) {
            red[wave][r*8+0]=l1[r];  red[wave][r*8+1]=l2[r];
            red[wave][r*8+2]=s1x[r]; red[wave][r*8+3]=s1y[r]; red[wave][r*8+4]=s1z[r];
            red[wave][r*8+5]=s2x[r]; red[wave][r*8+6]=s2y[r]; red[wave][r*8+7]=s2z[r];
        }
    }
    __syncthreads();

    // normalization folded into exponent constant
    float cc1[TR];
#pragma unroll
    for (int r = 0; r < TR; r++) {
        const float l1t = red[0][r*8] + red[1][r*8] + red[2][r*8] + red[3][r*8];
        cc1[r] = hc1[r] - LOG2F(l1t);
    }

    // ---- Pass B: write a1 (nontemporal stream) ----
    for (int it = 0; it < NIT; it++) {
        const int j0 = it * JT + tid * 4;
        const f32x4 xa = *(const f32x4*)(x + 3*j0);
        const f32x4 xb = *(const f32x4*)(x + 3*j0 + 4);
        const f32x4 xc = *(const f32x4*)(x + 3*j0 + 8);
        const float xs[12] = { xa.x, xa.y, xa.z, xa.w, xb.x, xb.y,
                               xb.z, xb.w, xc.x, xc.y, xc.z, xc.w };
#pragma unroll
        for (int r = 0; r < TR; r++) {
            f32x4 pv;
            pv.x = EXP2F(fmaf(h1z[r], xs[2],  fmaf(h1y[r], xs[1],  fmaf(h1x[r], xs[0],  cc1[r]))));
            pv.y = EXP2F(fmaf(h1z[r], xs[5],  fmaf(h1y[r], xs[4],  fmaf(h1x[r], xs[3],  cc1[r]))));
            pv.z = EXP2F(fmaf(h1z[r], xs[8],  fmaf(h1y[r], xs[7],  fmaf(h1x[r], xs[6],  cc1[r]))));
            pv.w = EXP2F(fmaf(h1z[r], xs[11], fmaf(h1y[r], xs[10], fmaf(h1x[r], xs[9],  cc1[r]))));
            __builtin_nontemporal_store(pv, (f32x4*)(out + (size_t)(row0 + r) * N_ROWS + j0));
        }
    }

    // ---- epilogue: b = Wb*(V1*(s1/l1)+bv1 + V2*(s2/l2)+bv2) + bb ----
    if (tid < TR) {
        const int r = tid;
        const float l1t = red[0][r*8+0]+red[1][r*8+0]+red[2][r*8+0]+red[3][r*8+0];
        const float l2t = red[0][r*8+1]+red[1][r*8+1]+red[2][r*8+1]+red[3][r*8+1];
        const float ux1 = (red[0][r*8+2]+red[1][r*8+2]+red[2][r*8+2]+red[3][r*8+2]) / l1t;
        const float uy1 = (red[0][r*8+3]+red[1][r*8+3]+red[2][r*8+3]+red[3][r*8+3]) / l1t;
        const float uz1 = (red[0][r*8+4]+red[1][r*8+4]+red[2][r*8+4]+red[3][r*8+4]) / l1t;
        const float ux2 = (red[0][r*8+5]+red[1][r*8+5]+red[2][r*8+5]+red[3][r*8+5]) / l2t;
        const float uy2 = (red[0][r*8+6]+red[1][r*8+6]+red[2][r*8+6]+red[3][r*8+6]) / l2t;
        const float uz2 = (red[0][r*8+7]+red[1][r*8+7]+red[2][r*8+7]+red[3][r*8+7]) / l2t;
        // normalized o = V1*u1 + bv1 + V2*u2 + bv2
        const float ox = v1w[0]*ux1 + v1w[1]*uy1 + v1w[2]*uz1 + v1b[0]
                       + v2w[0]*ux2 + v2w[1]*uy2 + v2w[2]*uz2 + v2b[0];
        const float oy = v1w[3]*ux1 + v1w[4]*uy1 + v1w[5]*uz1 + v1b[1]
                       + v2w[3]*ux2 + v2w[4]*uy2 + v2w[5]*uz2 + v2b[1];
        const float oz = v1w[6]*ux1 + v1w[7]*uy1 + v1w[8]*uz1 + v1b[2]
                       + v2w[6]*ux2 + v2w[7]*uy2 + v2w[8]*uz2 + v2b[2];
        const float b0 = wb[0]*ox + wb[1]*oy + wb[2]*oz + bb[0];
        const float b1 = wb[3]*ox + wb[4]*oy + wb[5]*oz + bb[1];
        const float b2 = wb[6]*ox + wb[7]*oy + wb[8]*oz + bb[2];
        const size_t base = (size_t)N_ROWS * N_ROWS + (size_t)(row0 + r) * 3;
        out[base+0] = b0; out[base+1] = b1; out[base+2] = b2;
    }
}

extern "C" void kernel_launch(void* const* d_in, const int* in_sizes, int n_in,
                              void* d_out, int out_size, void* d_ws, size_t ws_size,
                              hipStream_t stream) {
    const float* x   = (const float*)d_in[0];
    const float* wq1 = (const float*)d_in[1];  const float* bq1 = (const float*)d_in[2];
    const float* wq2 = (const float*)d_in[3];  const float* bq2 = (const float*)d_in[4];
    const float* wq3 = (const float*)d_in[5];  const float* bq3 = (const float*)d_in[6];
    const float* wq4 = (const float*)d_in[7];  const float* bq4 = (const float*)d_in[8];
    const float* wk1 = (const float*)d_in[9];  const float* bk1 = (const float*)d_in[10];
    const float* wk2 = (const float*)d_in[11]; const float* bk2 = (const float*)d_in[12];
    const float* wv1 = (const float*)d_in[13]; const float* bv1 = (const float*)d_in[14];
    const float* wv2 = (const float*)d_in[15]; const float* bv2 = (const float*)d_in[16];
    const float* wb  = (const float*)d_in[17]; const float* bb  = (const float*)d_in[18];

    float* out = (float*)d_out;

    attn_fused<<<NBLK, NT, 0, stream>>>(
        x, wq1,bq1, wq2,bq2, wq3,bq3, wq4,bq4,
        wk1,bk1, wk2,bk2, wv1,bv1, wv2,bv2, wb, bb, out);
}